// Round 2
// baseline (144.900 us; speedup 1.0000x reference)
//
#include <hip/hip_runtime.h>
#include <hip/hip_bf16.h>
#include <hip/hip_cooperative_groups.h>

namespace cg = cooperative_groups;

// Problem constants (B, N1, N2, D) = (256, 32, 32, 512)
#define BB 256
#define NN 32
#define DD 512

// Single cooperative kernel, grid = 256 blocks x 256 threads (1 block/CU).
// Phase 1: block j reduces ner row j -> u[j][:]  (threads 0..127, float4)
//          and face row j -> vT[:][j]            (threads 128..255, float4)
// grid.sync()
// Phase 2: block b computes logits[b][t] = u[b]·v[t]/(N1*N2) for t=0..255,
//          row logsumexp in LDS, then atomicAdd(-(diag-lse)/B) into out.
__global__ __launch_bounds__(256) void fused_batch_softmax(
    const float* __restrict__ face, const float* __restrict__ ner,
    float* __restrict__ u, float* __restrict__ vT, float* __restrict__ out) {
  cg::grid_group grid = cg::this_grid();
  const int j = blockIdx.x;
  const int t = threadIdx.x;

  // zero the (0xAA-poisoned) output via device-scope atomic so the later
  // cross-XCD atomicAdds see it at the coherence point
  if (j == 0 && t == 0) atomicExch(out, 0.0f);

  // ---- Phase 1: row sums ----
  {
    const bool is_ner = (t < 128);
    const int d4 = t & 127;  // DD/4 = 128 float4 groups per row
    const float* src = is_ner ? ner : face;
    const float4* p = (const float4*)(src + (size_t)j * NN * DD) + d4;
    float4 s = make_float4(0.f, 0.f, 0.f, 0.f);
#pragma unroll
    for (int n = 0; n < NN; ++n) {
      float4 x = p[n * (DD / 4)];
      s.x += x.x; s.y += x.y; s.z += x.z; s.w += x.w;
    }
    if (is_ner) {
      ((float4*)(u + (size_t)j * DD))[d4] = s;
    } else {
      int d = d4 * 4;
      vT[(size_t)(d + 0) * BB + j] = s.x;
      vT[(size_t)(d + 1) * BB + j] = s.y;
      vT[(size_t)(d + 2) * BB + j] = s.z;
      vT[(size_t)(d + 3) * BB + j] = s.w;
    }
  }

  grid.sync();  // device-scope: u/vT visible to all XCDs

  // ---- Phase 2: logits row j, logsumexp, diagonal ----
  __shared__ float us[DD];
  __shared__ float red[BB];
  __shared__ float diag_s;

  us[t]       = u[(size_t)j * DD + t];
  us[t + 256] = u[(size_t)j * DD + 256 + t];
  __syncthreads();

  float acc = 0.f;
#pragma unroll 8
  for (int d = 0; d < DD; ++d) {
    acc = fmaf(us[d], vT[(size_t)d * BB + t], acc);  // coalesced across lanes
  }
  float logit = acc * (1.f / (NN * NN));

  if (t == j) diag_s = logit;
  red[t] = logit;
  __syncthreads();
  for (int s = 128; s > 0; s >>= 1) {
    if (t < s) red[t] = fmaxf(red[t], red[t + s]);
    __syncthreads();
  }
  float mx = red[0];
  __syncthreads();
  red[t] = expf(logit - mx);
  __syncthreads();
  for (int s = 128; s > 0; s >>= 1) {
    if (t < s) red[t] += red[t + s];
    __syncthreads();
  }
  if (t == 0) {
    float lse = mx + logf(red[0]);
    atomicAdd(out, -(diag_s - lse) * (1.f / BB));
  }
}

extern "C" void kernel_launch(void* const* d_in, const int* in_sizes, int n_in,
                              void* d_out, int out_size, void* d_ws, size_t ws_size,
                              hipStream_t stream) {
  // setup_inputs dict order: face_j first, ner_j second
  const float* face = (const float*)d_in[0];  // (B, N2, D)
  const float* ner  = (const float*)d_in[1];  // (B, N1, D)
  float* u  = (float*)d_ws;          // B*D floats (512 KB)
  float* vT = u + (size_t)BB * DD;   // D*B floats (512 KB)
  float* out = (float*)d_out;

  void* args[] = {(void*)&face, (void*)&ner, (void*)&u, (void*)&vT, (void*)&out};
  hipLaunchCooperativeKernel((const void*)fused_batch_softmax,
                             dim3(BB), dim3(256), args, 0, stream);
}

// Round 3
// 95.085 us; speedup vs baseline: 1.5239x; 1.5239x over previous
//
#include <hip/hip_runtime.h>
#include <hip/hip_bf16.h>

// Problem constants (B, N1, N2, D) = (256, 32, 32, 512)
#define BB 256
#define NN 32
#define DD 512
#define ROWS 4  // rows of logits per block in row_lse4

// Kernel 1: u[b][d] = sum_n ner[b][n][d];  vT[d][c] = sum_f face[c][f][d]
// One thread per float4 output group. First half of grid -> ner, second -> face.
// Also zeroes out[0] (poisoned 0xAA by harness); visibility to kernel 2 is
// guaranteed by stream ordering (L2 writeback at dispatch end).
__global__ __launch_bounds__(256) void reduce_sums(
    const float* __restrict__ ner, const float* __restrict__ face,
    float* __restrict__ u, float* __restrict__ vT, float* __restrict__ out) {
  int idx = blockIdx.x * 256 + threadIdx.x;
  if (idx == 0) out[0] = 0.0f;
  const int half = BB * DD / 4;  // 32768 float4 outputs per tensor
  bool is_ner = idx < half;
  int j = is_ner ? idx : idx - half;
  int row = j >> 7;        // DD/4 = 128 float4 per row
  int d4  = j & 127;
  const float* src = is_ner ? ner : face;
  const float4* p = (const float4*)(src + (size_t)row * NN * DD) + d4;
  float4 s = make_float4(0.f, 0.f, 0.f, 0.f);
#pragma unroll
  for (int n = 0; n < NN; ++n) {
    float4 x = p[n * (DD / 4)];
    s.x += x.x; s.y += x.y; s.z += x.z; s.w += x.w;
  }
  if (is_ner) {
    ((float4*)(u + (size_t)row * DD))[d4] = s;
  } else {
    int d = d4 * 4;
    vT[(size_t)(d + 0) * BB + row] = s.x;
    vT[(size_t)(d + 1) * BB + row] = s.y;
    vT[(size_t)(d + 2) * BB + row] = s.z;
    vT[(size_t)(d + 3) * BB + row] = s.w;
  }
}

// Kernel 2: block handles ROWS=4 consecutive logits rows. Streams vT once
// (32 MB aggregate L2 traffic vs 128 MB at 1 row/block), 4 accumulators for
// ILP. Wave w does the logsumexp for row w via 64-lane shuffles. One
// atomicAdd per block accumulates -(diag - lse)/B into out.
__global__ __launch_bounds__(256) void row_lse4(
    const float* __restrict__ u, const float* __restrict__ vT,
    float* __restrict__ out) {
  const int b0 = blockIdx.x * ROWS;
  const int t = threadIdx.x;
  __shared__ float us[ROWS * DD];   // 8 KB
  __shared__ float ls[ROWS][BB];    // 4 KB
  __shared__ float wsum[ROWS];

  const float4* usrc = (const float4*)(u + (size_t)b0 * DD);
#pragma unroll
  for (int i = 0; i < (ROWS * DD / 4) / 256; ++i)  // 2 iterations
    ((float4*)us)[t + i * 256] = usrc[t + i * 256];
  __syncthreads();

  float acc0 = 0.f, acc1 = 0.f, acc2 = 0.f, acc3 = 0.f;
#pragma unroll 8
  for (int d = 0; d < DD; ++d) {
    float v = vT[(size_t)d * BB + t];  // coalesced across lanes
    acc0 = fmaf(us[0 * DD + d], v, acc0);  // LDS broadcast, conflict-free
    acc1 = fmaf(us[1 * DD + d], v, acc1);
    acc2 = fmaf(us[2 * DD + d], v, acc2);
    acc3 = fmaf(us[3 * DD + d], v, acc3);
  }
  const float sc = 1.f / (NN * NN);
  ls[0][t] = acc0 * sc;
  ls[1][t] = acc1 * sc;
  ls[2][t] = acc2 * sc;
  ls[3][t] = acc3 * sc;
  __syncthreads();

  // wave w reduces row w (4 waves, 4 rows)
  const int w = t >> 6;
  const int lane = t & 63;
  float x0 = ls[w][lane];
  float x1 = ls[w][lane + 64];
  float x2 = ls[w][lane + 128];
  float x3 = ls[w][lane + 192];
  float m = fmaxf(fmaxf(x0, x1), fmaxf(x2, x3));
#pragma unroll
  for (int off = 32; off > 0; off >>= 1) m = fmaxf(m, __shfl_xor(m, off, 64));
  float e = __expf(x0 - m) + __expf(x1 - m) + __expf(x2 - m) + __expf(x3 - m);
#pragma unroll
  for (int off = 32; off > 0; off >>= 1) e += __shfl_xor(e, off, 64);
  if (lane == 0) {
    float lse = m + __logf(e);
    float diag = ls[w][b0 + w];
    wsum[w] = diag - lse;
  }
  __syncthreads();
  if (t == 0) {
    atomicAdd(out, -(wsum[0] + wsum[1] + wsum[2] + wsum[3]) * (1.f / BB));
  }
}

extern "C" void kernel_launch(void* const* d_in, const int* in_sizes, int n_in,
                              void* d_out, int out_size, void* d_ws, size_t ws_size,
                              hipStream_t stream) {
  // setup_inputs dict order: face_j first, ner_j second
  const float* face = (const float*)d_in[0];  // (B, N2, D)
  const float* ner  = (const float*)d_in[1];  // (B, N1, D)
  float* u  = (float*)d_ws;          // B*D floats (512 KB)
  float* vT = u + (size_t)BB * DD;   // D*B floats (512 KB)
  float* out = (float*)d_out;

  const int total_threads = 2 * BB * DD / 4;  // 65536
  reduce_sums<<<total_threads / 256, 256, 0, stream>>>(ner, face, u, vT, out);
  row_lse4<<<BB / ROWS, 256, 0, stream>>>(u, vT, out);
}

// Round 4
// 81.126 us; speedup vs baseline: 1.7861x; 1.1721x over previous
//
#include <hip/hip_runtime.h>
#include <hip/hip_bf16.h>

// Problem constants (B, N1, N2, D) = (256, 32, 32, 512)
#define BB 256
#define NN 32
#define DD 512
#define ROWS 2    // logits rows per block in row_lse_bf16
#define KSPLIT 4  // D-dimension split inside a block

static __device__ inline unsigned f2bf(float x) {
  union { float f; unsigned u; } a; a.f = x;
  unsigned r = a.u + 0x7fff + ((a.u >> 16) & 1);  // round-to-nearest-even
  return r >> 16;
}

// Kernel 1: u[b][d] = sum_n ner[b][n][d] (fp32);
//           vTp[d/2][c] = bf16x2(sum_f face[c][f][d], ... [d+1]) packed dword.
// One thread per float4 output group; blocks 0-127 ner, 128-255 face.
// Also zeroes out[0] (harness poisons 0xAA); stream order makes it visible to K2.
__global__ __launch_bounds__(256) void reduce_sums(
    const float* __restrict__ ner, const float* __restrict__ face,
    float* __restrict__ u, unsigned* __restrict__ vTp, float* __restrict__ out) {
  int idx = blockIdx.x * 256 + threadIdx.x;
  if (idx == 0) out[0] = 0.0f;
  const int half = BB * DD / 4;  // 32768 float4 outputs per tensor
  bool is_ner = idx < half;
  int j = is_ner ? idx : idx - half;
  int row = j >> 7;   // DD/4 = 128 float4 per row
  int d4  = j & 127;
  const float* src = is_ner ? ner : face;
  const float4* p = (const float4*)(src + (size_t)row * NN * DD) + d4;
  float4 s = make_float4(0.f, 0.f, 0.f, 0.f);
#pragma unroll
  for (int n = 0; n < NN; ++n) {
    float4 x = p[n * (DD / 4)];
    s.x += x.x; s.y += x.y; s.z += x.z; s.w += x.w;
  }
  if (is_ner) {
    ((float4*)(u + (size_t)row * DD))[d4] = s;
  } else {
    // d = 4*d4 .. 4*d4+3 ; dp = d>>1 ; low 16 bits = even d (unpacked as w<<16)
    int dp0 = 2 * d4;
    vTp[(size_t)dp0 * BB + row]       = (f2bf(s.y) << 16) | f2bf(s.x);
    vTp[(size_t)(dp0 + 1) * BB + row] = (f2bf(s.w) << 16) | f2bf(s.z);
  }
}

// Kernel 2: 128 blocks x 1024 threads. Block handles ROWS=2 logits rows.
// Thread (c = t&255, k = t>>8) accumulates a 128-d chunk of the dot for both
// rows; k-partials combined in LDS; wave w does row-w logsumexp via shuffles;
// one atomicAdd per block into out.
__global__ __launch_bounds__(1024) void row_lse_bf16(
    const float* __restrict__ u, const unsigned* __restrict__ vTp,
    float* __restrict__ out) {
  const int b0 = blockIdx.x * ROWS;
  const int t = threadIdx.x;
  const int c = t & 255;
  const int k = t >> 8;  // 0..3
  __shared__ float us[ROWS * DD];         // 4 KB (fp32 u rows)
  __shared__ float ls[KSPLIT][ROWS][BB];  // 8 KB (k-partials)
  __shared__ float lg[ROWS][BB];          // 2 KB (logits)
  __shared__ float wsum[ROWS];

  if (t < ROWS * DD / 4)  // 256 threads stage 2 rows of u as float4
    ((float4*)us)[t] = ((const float4*)(u + (size_t)b0 * DD))[t];
  __syncthreads();

  float a0l = 0.f, a0h = 0.f, a1l = 0.f, a1h = 0.f;
  const unsigned* p = vTp + (size_t)(k * (DD / 2 / KSPLIT)) * BB + c;
  const float* u0 = us + k * (DD / KSPLIT);
  const float* u1 = us + DD + k * (DD / KSPLIT);
#pragma unroll 8
  for (int i = 0; i < DD / 2 / KSPLIT; ++i) {  // 64 dword loads, coalesced in c
    unsigned w = p[(size_t)i * BB];
    float vlo = __uint_as_float(w << 16);          // even d
    float vhi = __uint_as_float(w & 0xffff0000u);  // odd d
    a0l = fmaf(u0[2 * i],     vlo, a0l);  // LDS broadcast reads, conflict-free
    a0h = fmaf(u0[2 * i + 1], vhi, a0h);
    a1l = fmaf(u1[2 * i],     vlo, a1l);
    a1h = fmaf(u1[2 * i + 1], vhi, a1h);
  }
  ls[k][0][c] = a0l + a0h;
  ls[k][1][c] = a1l + a1h;
  __syncthreads();

  const float sc = 1.f / (NN * NN);
  if (t < ROWS * BB) {  // combine k-partials: 512 threads, stride-1 in c
    int cc = t & 255, r = t >> 8;
    lg[r][cc] = (ls[0][r][cc] + ls[1][r][cc] + ls[2][r][cc] + ls[3][r][cc]) * sc;
  }
  __syncthreads();

  const int wv = t >> 6, lane = t & 63;
  if (wv < ROWS) {  // wave wv reduces row wv
    float x0 = lg[wv][lane];
    float x1 = lg[wv][lane + 64];
    float x2 = lg[wv][lane + 128];
    float x3 = lg[wv][lane + 192];
    float m = fmaxf(fmaxf(x0, x1), fmaxf(x2, x3));
#pragma unroll
    for (int off = 32; off > 0; off >>= 1) m = fmaxf(m, __shfl_xor(m, off, 64));
    float e = __expf(x0 - m) + __expf(x1 - m) + __expf(x2 - m) + __expf(x3 - m);
#pragma unroll
    for (int off = 32; off > 0; off >>= 1) e += __shfl_xor(e, off, 64);
    if (lane == 0) wsum[wv] = lg[wv][b0 + wv] - (m + __logf(e));
  }
  __syncthreads();
  if (t == 0) atomicAdd(out, -(wsum[0] + wsum[1]) * (1.f / BB));
}

extern "C" void kernel_launch(void* const* d_in, const int* in_sizes, int n_in,
                              void* d_out, int out_size, void* d_ws, size_t ws_size,
                              hipStream_t stream) {
  // setup_inputs dict order: face_j first, ner_j second
  const float* face = (const float*)d_in[0];  // (B, N2, D)
  const float* ner  = (const float*)d_in[1];  // (B, N1, D)
  float* u = (float*)d_ws;                       // 256*512 f32 = 512 KB
  unsigned* vTp = (unsigned*)(u + (size_t)BB * DD);  // 256*256 u32 = 256 KB
  float* out = (float*)d_out;

  const int total_threads = 2 * BB * DD / 4;  // 65536
  reduce_sums<<<total_threads / 256, 256, 0, stream>>>(ner, face, u, vTp, out);
  row_lse_bf16<<<BB / ROWS, 1024, 0, stream>>>(u, vTp, out);
}